// Round 18
// baseline (67.941 us; speedup 1.0000x reference)
//
#include <hip/hip_runtime.h>

// Deformable conv2d (N=4, C=OC=256, 80x80, 3x3, s1 p1 d1):
// fused bilinear-im2col + bf16 MFMA GEMM, fp32 accumulate.
// R18 = R17 mechanisms + UNIFORM GRID: 400 blocks (1.56/CU, wall=2 rounds)
//   -> 256 blocks = 1/CU exactly, via exact mixed tiling per image:
//   6400 px = 48x112 + 16x64. Block body templated <NFRAG=7|4>; no masks,
//   all fragments full. Slab double-buffered (61KB LDS). 112-px sampling
//   runs 2 rounds (512+384 thr) with separately-named round-2 registers.

typedef short short8 __attribute__((ext_vector_type(8)));
typedef float floatx4 __attribute__((ext_vector_type(4)));
typedef float floatx2 __attribute__((ext_vector_type(2)));
typedef unsigned int uint4v __attribute__((ext_vector_type(4)));

#define Cc    256
#define OCc   256
#define Hh    80
#define Ww    80
#define HW    6400
#define KK    9
#define Ktot  2304
#define KC    64            // K per chunk = one tap x 64 channels
#define NCHUNK (Ktot / KC)  // 36
#define NKB   (Ktot / 32)   // 72
#define PTMAX 112
#define WP_ELEMS (Ktot * OCc)          // 589824 ushorts (1.18 MB)
#define XT_OFF   ((size_t)WP_ELEMS)
#define PREP_W_BLOCKS 288

#define BARRIER_LDS()                                      \
  do {                                                     \
    asm volatile("s_waitcnt lgkmcnt(0)" ::: "memory");     \
    __builtin_amdgcn_s_barrier();                          \
  } while (0)

__device__ __forceinline__ unsigned short f2bf(float f) {
  unsigned u = __float_as_uint(f);
  u += 0x7FFF + ((u >> 16) & 1);
  return (unsigned short)(u >> 16);
}
__device__ __forceinline__ unsigned int cvtpk(float lo, float hi) {
  unsigned int r;
  asm("v_cvt_pk_bf16_f32 %0, %1, %2" : "=v"(r) : "v"(lo), "v"(hi));
  return r;
}

// ---- Kernel 1 (merged prep): [0,288): weight->bf16 A-frags tap-major;
//      [288,1888): x NCHW fp32 -> NHWC bf16.
__global__ void prep(const float* __restrict__ w, const float* __restrict__ x,
                     unsigned short* __restrict__ wp,
                     unsigned short* __restrict__ xt) {
  __shared__ float tile[64][65];
  const int tid = threadIdx.x;
  if (blockIdx.x < PREP_W_BLOCKS) {
    const int t = blockIdx.x * 256 + tid;
    const int lane = t & 63;
    const int ocf  = (t >> 6) & 15;
    const int kb   = t >> 10;
    const int oc   = ocf * 16 + (lane & 15);
    const int k0   = kb * 32 + (lane >> 4) * 8;
    const int tap  = k0 >> 8;
    const int c0   = k0 & 255;
    const float* src = w + (size_t)oc * Ktot + (size_t)c0 * KK + tap;
    short8 pk;
    #pragma unroll
    for (int e = 0; e < 8; ++e) pk[e] = (short)f2bf(src[e * KK]);
    *(short8*)(wp + (size_t)t * 8) = pk;
    return;
  }
  const int b = blockIdx.x - PREP_W_BLOCKS;
  const int hw0 = (b % 100) * 64;
  const int c0  = ((b / 100) & 3) * 64;
  const int n   = b / 400;
  #pragma unroll
  for (int i = 0; i < 16; ++i) {
    const int idx = i * 256 + tid;
    const int cl = idx >> 6, hl = idx & 63;
    tile[cl][hl] = x[((size_t)(n * Cc + c0 + cl)) * HW + hw0 + hl];
  }
  __syncthreads();
  #pragma unroll
  for (int i = 0; i < 16; ++i) {
    const int idx = i * 256 + tid;
    const int hl = idx >> 6, cl = idx & 63;
    xt[((size_t)(n * HW + hw0 + hl)) * Cc + c0 + cl] = f2bf(tile[cl][hl]);
  }
}

// ---- Templated block body: NFRAG px-fragments (7 -> 112px, 4 -> 64px) ----
template <int NFRAG>
__device__ __forceinline__ void dcn_body(
    const int tid, const int lane, const int wv, const int nn, const int p0,
    const float* __restrict__ offset, const unsigned short* __restrict__ wp,
    const char* __restrict__ xn, float* __restrict__ out,
    char* __restrict__ slab, float4* __restrict__ s_w, int4* __restrict__ s_i) {
  constexpr int PTl = NFRAG * 16;
  constexpr int SLOTS = PTl * 8;        // sampling slots (px x cg)

  // ---- Phase 0: bilinear coords; masks folded into per-corner weights ----
  for (int s = tid; s < KK * PTl; s += 512) {
    const int k = s / PTl, p = s % PTl;
    const int pp = p0 + p;
    const int oy = pp / Ww, ox = pp % Ww;
    const int ky = k / 3, kx = k % 3;
    const float offy = offset[(size_t)(nn * 18 + 2 * k    ) * HW + pp];
    const float offx = offset[(size_t)(nn * 18 + 2 * k + 1) * HW + pp];
    const float py = offy + (float)(ky + oy - 1);
    const float px = offx + (float)(kx + ox - 1);
    const float fy0 = floorf(py), fx0 = floorf(px);
    const int iy0 = (int)fy0, ix0 = (int)fx0;
    const float wy1 = py - fy0, wx1 = px - fx0;
    const float wy0 = 1.f - wy1, wx0 = 1.f - wx1;
    const bool my0 = (iy0     >= 0) & (iy0     < Hh);
    const bool my1 = (iy0 + 1 >= 0) & (iy0 + 1 < Hh);
    const bool mx0 = (ix0     >= 0) & (ix0     < Ww);
    const bool mx1 = (ix0 + 1 >= 0) & (ix0 + 1 < Ww);
    const int cy0 = min(max(iy0,     0), Hh - 1);
    const int cy1 = min(max(iy0 + 1, 0), Hh - 1);
    const int cx0 = min(max(ix0,     0), Ww - 1);
    const int cx1 = min(max(ix0 + 1, 0), Ww - 1);
    float4 w4;
    w4.x = wx0 * wy0 * ((my0 && mx0) ? 1.f : 0.f);
    w4.y = wx1 * wy0 * ((my0 && mx1) ? 1.f : 0.f);
    w4.z = wx0 * wy1 * ((my1 && mx0) ? 1.f : 0.f);
    w4.w = wx1 * wy1 * ((my1 && mx1) ? 1.f : 0.f);
    int4 i4;
    i4.x = (cy0 * Ww + cx0) * 512;  i4.y = (cy0 * Ww + cx1) * 512;
    i4.z = (cy1 * Ww + cx0) * 512;  i4.w = (cy1 * Ww + cx1) * 512;
    s_w[s] = w4;
    s_i[s] = i4;
  }

  floatx4 acc[2][NFRAG] = {};
  const int lm = lane & 15, lg = lane >> 4;
  const int spx1 = tid >> 3;            // round-1 sampling pixel
  const int cg   = tid & 7;             // channel group (both rounds)
  const int spx2 = 64 + (tid >> 3);     // round-2 sampling pixel (NFRAG=7)
  const bool r2  = (NFRAG == 7) && (tid < (SLOTS - 512));
  const int wbyte1 = spx1 * 128 + ((cg * 16) ^ ((spx1 & 7) << 4));
  const int wbyte2 = spx2 * 128 + ((cg * 16) ^ ((spx2 & 7) << 4));
  __syncthreads();

  // Named in-flight register sets (rule #20).
  short8 raA, rbA, rcA, rdA, raB, rbB, rcB, rdB;          // gathers round 1
  short8 reA, rfA, rgA, rhA, reB, rfB, rgB, rhB;          // gathers round 2
  short8 fA00, fA01, fA10, fA11, fB00, fB01, fB10, fB11;  // A-frags

  #define ISSUE(ch, S)                                                  \
    { const int tap_ = (ch) >> 2;                                       \
      const int coff_ = (((ch) & 3) * KC + cg * 8) * 2;                 \
      const int4 i1_ = s_i[tap_ * PTl + spx1];                          \
      ra##S = *(const short8*)(xn + i1_.x + coff_);                     \
      rb##S = *(const short8*)(xn + i1_.y + coff_);                     \
      rc##S = *(const short8*)(xn + i1_.z + coff_);                     \
      rd##S = *(const short8*)(xn + i1_.w + coff_);                     \
      if constexpr (NFRAG == 7) if (r2) {                               \
        const int4 i2_ = s_i[tap_ * PTl + spx2];                        \
        re##S = *(const short8*)(xn + i2_.x + coff_);                   \
        rf##S = *(const short8*)(xn + i2_.y + coff_);                   \
        rg##S = *(const short8*)(xn + i2_.z + coff_);                   \
        rh##S = *(const short8*)(xn + i2_.w + coff_);                   \
      } }

  #define PREFA(ch, S)                                                  \
    { const unsigned short* w0_ = wp + (size_t)((ch) * 2) * (16 * 64 * 8) \
                                     + (size_t)((wv * 2) * 64 + lane) * 8; \
      f##S##00 = *(const short8*)(w0_);                                 \
      f##S##01 = *(const short8*)(w0_ + 64 * 8);                        \
      f##S##10 = *(const short8*)(w0_ + 16 * 64 * 8);                   \
      f##S##11 = *(const short8*)(w0_ + 16 * 64 * 8 + 64 * 8); }

  #define COMBINE(pa, pb, pc, pd, w4_, dst_)                            \
    { const uint4v ua_ = __builtin_bit_cast(uint4v, pa);                \
      const uint4v ub_ = __builtin_bit_cast(uint4v, pb);                \
      const uint4v uc_ = __builtin_bit_cast(uint4v, pc);                \
      const uint4v ud_ = __builtin_bit_cast(uint4v, pd);                \
      _Pragma("unroll")                                                 \
      for (int r_ = 0; r_ < 4; ++r_) {                                  \
        floatx2 va_, vb_, vc_, vd_;                                     \
        va_[0] = __uint_as_float(ua_[r_] << 16);                        \
        va_[1] = __uint_as_float(ua_[r_] & 0xFFFF0000u);                \
        vb_[0] = __uint_as_float(ub_[r_] << 16);                        \
        vb_[1] = __uint_as_float(ub_[r_] & 0xFFFF0000u);                \
        vc_[0] = __uint_as_float(uc_[r_] << 16);                        \
        vc_[1] = __uint_as_float(uc_[r_] & 0xFFFF0000u);                \
        vd_[0] = __uint_as_float(ud_[r_] << 16);                        \
        vd_[1] = __uint_as_float(ud_[r_] & 0xFFFF0000u);                \
        const floatx2 v_ = w4_.x * va_ + w4_.y * vb_                    \
                         + w4_.z * vc_ + w4_.w * vd_;                   \
        dst_[r_] = cvtpk(v_[0], v_[1]);                                 \
      } }

  #define FINISH(ch, S)                                                 \
    { const int tap_ = (ch) >> 2;                                       \
      char* buf_ = slab + ((ch) & 1) * (PTl * 128);                     \
      { const float4 w4_ = s_w[tap_ * PTl + spx1];                      \
        uint4v pk_;                                                     \
        COMBINE(ra##S, rb##S, rc##S, rd##S, w4_, pk_);                  \
        *(uint4v*)(buf_ + wbyte1) = pk_; }                              \
      if constexpr (NFRAG == 7) if (r2) {                               \
        const float4 w4_ = s_w[tap_ * PTl + spx2];                      \
        uint4v pk_;                                                     \
        COMBINE(re##S, rf##S, rg##S, rh##S, w4_, pk_);                  \
        *(uint4v*)(buf_ + wbyte2) = pk_; } }

  #define MFMA_STEP(ch, S)                                              \
    { const char* base_ = slab + ((ch) & 1) * (PTl * 128);              \
      __builtin_amdgcn_s_setprio(1);                                    \
      _Pragma("unroll")                                                 \
      for (int ks = 0; ks < 2; ++ks) {                                  \
        short8 b_[NFRAG];                                               \
        _Pragma("unroll")                                               \
        for (int j = 0; j < NFRAG; ++j) {                               \
          const int px_ = j * 16 + lm;                                  \
          const int byte_ = px_ * 128 + (((ks * 64) + lg * 16) ^ ((px_ & 7) << 4)); \
          b_[j] = *(const short8*)(base_ + byte_);                      \
        }                                                               \
        const short8 a0_ = ks ? f##S##10 : f##S##00;                    \
        const short8 a1_ = ks ? f##S##11 : f##S##01;                    \
        _Pragma("unroll")                                               \
        for (int j = 0; j < NFRAG; ++j)                                 \
          acc[0][j] = __builtin_amdgcn_mfma_f32_16x16x32_bf16(a0_, b_[j], acc[0][j], 0, 0, 0); \
        _Pragma("unroll")                                               \
        for (int j = 0; j < NFRAG; ++j)                                 \
          acc[1][j] = __builtin_amdgcn_mfma_f32_16x16x32_bf16(a1_, b_[j], acc[1][j], 0, 0, 0); \
      }                                                                 \
      __builtin_amdgcn_s_setprio(0); }

  // ---- Prologue ----
  PREFA(0, A);
  ISSUE(0, A);
  FINISH(0, A);
  ISSUE(1, A);
  BARRIER_LDS();

  // ---- Main loop (2 chunks/iter) ----
  for (int it = 0; it < NCHUNK / 2; ++it) {
    const int ch = it * 2;
    MFMA_STEP(ch, A);
    PREFA(ch + 1, B);
    if (ch + 2 < NCHUNK) ISSUE(ch + 2, B);
    FINISH(ch + 1, A);
    BARRIER_LDS();
    MFMA_STEP(ch + 1, B);
    if (ch + 2 < NCHUNK) PREFA(ch + 2, A);
    if (ch + 3 < NCHUNK) ISSUE(ch + 3, A);
    if (ch + 2 < NCHUNK) FINISH(ch + 2, B);
    BARRIER_LDS();
  }

  // ---- Epilogue ----
  #pragma unroll
  for (int f = 0; f < 2; ++f) {
    const int oc = (wv * 2 + f) * 16 + lg * 4;
    #pragma unroll
    for (int j = 0; j < NFRAG; ++j) {
      const int px = p0 + j * 16 + lm;
      #pragma unroll
      for (int r = 0; r < 4; ++r) {
        out[(size_t)(nn * OCc + oc + r) * HW + px] = acc[f][j][r];
      }
    }
  }
  #undef ISSUE
  #undef PREFA
  #undef COMBINE
  #undef FINISH
  #undef MFMA_STEP
}

// ---- Kernel 2: 256 blocks (1/CU), mixed 112/64-px tiles ----
__global__ __launch_bounds__(512, 2) void dcn_mfma(
    const float* __restrict__ offset, const unsigned short* __restrict__ wp,
    const unsigned short* __restrict__ xt, float* __restrict__ out) {
  __shared__ unsigned short s_col[2][PTMAX * KC];  // 28.7 KB
  __shared__ float4 s_w[KK * PTMAX];               // 16.1 KB
  __shared__ int4   s_i[KK * PTMAX];               // 16.1 KB

  const int tid  = threadIdx.x;
  const int lane = tid & 63;
  const int wv   = tid >> 6;

  // XCD swizzle: 256 = 8 XCDs x 32 contiguous blocks
  const int bid = blockIdx.x;
  const int logical = (bid & 7) * 32 + (bid >> 3);
  const int nn = logical >> 6;          // image
  const int b  = logical & 63;          // tile in image: 48x112px + 16x64px
  const char* xn = (const char*)(xt + (size_t)nn * HW * Cc);

  if (b < 48) {
    dcn_body<7>(tid, lane, wv, nn, b * 112, offset, wp, xn, out,
                (char*)s_col, s_w, s_i);
  } else {
    dcn_body<4>(tid, lane, wv, nn, 5376 + (b - 48) * 64, offset, wp, xn, out,
                (char*)s_col, s_w, s_i);
  }
}

extern "C" void kernel_launch(void* const* d_in, const int* in_sizes, int n_in,
                              void* d_out, int out_size, void* d_ws, size_t ws_size,
                              hipStream_t stream) {
  const float* x      = (const float*)d_in[0];
  const float* offset = (const float*)d_in[1];
  const float* weight = (const float*)d_in[2];
  float* out = (float*)d_out;
  unsigned short* wp = (unsigned short*)d_ws;              // 1.18 MB
  unsigned short* xt = (unsigned short*)d_ws + XT_OFF;     // 13.1 MB

  prep<<<dim3(PREP_W_BLOCKS + 1600), dim3(256), 0, stream>>>(weight, x, wp, xt);
  dcn_mfma<<<dim3(256), dim3(512), 0, stream>>>(offset, wp, xt, out);
}